// Round 10
// baseline (309.017 us; speedup 1.0000x reference)
//
#include <hip/hip_runtime.h>
#include <math.h>

#define TSEQ   2048
#define BB     2
#define DMODEL 1024
#define NHEAD  16
#define DHEAD  64
#define MROWS  (TSEQ * BB)   // 4096
#define NQB    (TSEQ / 64)   // 32 query tiles per (b,h)

typedef __attribute__((ext_vector_type(8))) _Float16 half8;
typedef __attribute__((ext_vector_type(4))) float    floatx4;
typedef unsigned short u16;
typedef unsigned int   u32;

#define QSCL 11.5415603f   /* 8 * log2(e): Q pre-scale -> exp2-domain scores */
#define MSK  1442695.0f    /* 1e6 * log2(e) */

__device__ __forceinline__ u16 f2h(float f) {
    union { _Float16 h; u16 u; } cv;
    cv.h = (_Float16)f;
    return cv.u;
}

// packed fp32x2 -> fp16x2 (round-to-zero) as u32
__device__ __forceinline__ u32 pkrtz(float a, float b) {
    typedef __attribute__((ext_vector_type(2))) __fp16 fp16x2;
    union { fp16x2 h; u32 u; } cv;
    cv.h = __builtin_amdgcn_cvt_pkrtz(a, b);
    return cv.u;
}

// ---------------------------------------------------------------------------
// one-launch fp32 -> fp16 cast of x, qkv_w, out_w
// float4 units: x 1048576, qkv_w 786432, out_w 262144 (total 2097152)
// ---------------------------------------------------------------------------
__global__ __launch_bounds__(256)
void cast3_f32_f16(const float* __restrict__ a, u16* __restrict__ oa,
                   const float* __restrict__ b, u16* __restrict__ ob,
                   const float* __restrict__ c, u16* __restrict__ oc)
{
    int i = blockIdx.x * 256 + threadIdx.x;
    const float* src; u16* dst; int off;
    if (i < 1048576)      { src = a; dst = oa; off = 0; }
    else if (i < 1835008) { src = b; dst = ob; off = 1048576; }
    else                  { src = c; dst = oc; off = 1835008; }
    int j = i - off;
    float4 v = ((const float4*)src)[j];
    ushort4 o;
    o.x = f2h(v.x); o.y = f2h(v.y); o.z = f2h(v.z); o.w = f2h(v.w);
    ((ushort4*)dst)[j] = o;
}

// ---------------------------------------------------------------------------
// QKV GEMM: 128(M) x 64(N) tile, BK=64, XOR-swizzled LDS.
// Staging = flash-style REGISTER PREFETCH: tile k+1 loaded into VGPRs right
// after the publishing barrier (vmcnt wait lands after the compute phase ->
// free), ds_write after the read-done barrier. Barriers never drain
// in-flight global loads (the m97 ~20% stall).
// c<2 (Q,K): transposed orientation, packed uint2 fp16 -> [b][h][t][d],
//            Q scaled by QSCL;  c==2 (V): normal -> V^T [b][h][d][t].
// ---------------------------------------------------------------------------
__global__ __launch_bounds__(256)
void gemm_qkv(const u16* __restrict__ A, const u16* __restrict__ W,
              const float* __restrict__ bias,
              u16* __restrict__ Qo, u16* __restrict__ Ko, u16* __restrict__ Vo,
              int M, int N, int K)
{
    __shared__ __align__(16) u16 As[128][64];
    __shared__ __align__(16) u16 Bs[64][64];

    const int tid  = threadIdx.x;
    const int lane = tid & 63;
    const int wv   = tid >> 6;
    const int ln   = lane & 15, lh = lane >> 4;
    const int m0   = blockIdx.y * 128;
    const int n0   = blockIdx.x * 64;

    const int c = n0 >> 10;                  // 0,1,2 = q,k,v (block-uniform)
    const bool vmode = (c == 2);             // normal orientation

    const int srowA = wv * 32 + (lane >> 3);   // + t*8, t=0..3
    const int srowW = wv * 16 + (lane >> 3);   // + t*8, t=0..1
    const int sslot = lane & 7;
    const int gcol  = (sslot ^ ((lane >> 3) & 7)) * 8;   // row&7 == (lane>>3)

    const u16* gA = A + (size_t)(m0 + srowA) * K + gcol;
    const u16* gW = W + (size_t)(n0 + srowW) * K + gcol;

    const floatx4 zero4 = {0.0f, 0.0f, 0.0f, 0.0f};
    floatx4 acc[2][4];
#pragma unroll
    for (int i = 0; i < 2; ++i)
#pragma unroll
        for (int j = 0; j < 4; ++j) acc[i][j] = zero4;

    uint4 ra[4], rb[2];
    // prologue: tile 0 -> regs -> LDS
#pragma unroll
    for (int t = 0; t < 4; ++t) ra[t] = *(const uint4*)(gA + (size_t)t * 8 * K);
#pragma unroll
    for (int t = 0; t < 2; ++t) rb[t] = *(const uint4*)(gW + (size_t)t * 8 * K);
#pragma unroll
    for (int t = 0; t < 4; ++t) *(uint4*)&As[srowA + t * 8][sslot * 8] = ra[t];
#pragma unroll
    for (int t = 0; t < 2; ++t) *(uint4*)&Bs[srowW + t * 8][sslot * 8] = rb[t];

    const int NIT = K / 64;
    for (int it = 0; it < NIT; ++it) {
        __syncthreads();                       // publish tile it (lgkm only)

        // prefetch tile it+1 into regs (latency hidden behind compute)
        if (it + 1 < NIT) {
            const int k0 = (it + 1) * 64;
#pragma unroll
            for (int t = 0; t < 4; ++t) ra[t] = *(const uint4*)(gA + (size_t)t * 8 * K + k0);
#pragma unroll
            for (int t = 0; t < 2; ++t) rb[t] = *(const uint4*)(gW + (size_t)t * 8 * K + k0);
        }

#pragma unroll
        for (int ks = 0; ks < 2; ++ks) {
            half8 xf[2], wf[4];
#pragma unroll
            for (int i = 0; i < 2; ++i) {
                const int row = wv * 32 + i * 16 + ln;
                xf[i] = *(const half8*)&As[row][(((ks << 2) | lh) ^ (row & 7)) * 8];
            }
#pragma unroll
            for (int j = 0; j < 4; ++j) {
                const int row = j * 16 + ln;
                wf[j] = *(const half8*)&Bs[row][(((ks << 2) | lh) ^ (row & 7)) * 8];
            }
            if (vmode) {
#pragma unroll
                for (int i = 0; i < 2; ++i)
#pragma unroll
                    for (int j = 0; j < 4; ++j)
                        acc[i][j] = __builtin_amdgcn_mfma_f32_16x16x32_f16(xf[i], wf[j], acc[i][j], 0, 0, 0);
            } else {
#pragma unroll
                for (int i = 0; i < 2; ++i)
#pragma unroll
                    for (int j = 0; j < 4; ++j)
                        acc[i][j] = __builtin_amdgcn_mfma_f32_16x16x32_f16(wf[j], xf[i], acc[i][j], 0, 0, 0);
            }
        }

        __syncthreads();                       // all reads of tile it done
        if (it + 1 < NIT) {
#pragma unroll
            for (int t = 0; t < 4; ++t) *(uint4*)&As[srowA + t * 8][sslot * 8] = ra[t];
#pragma unroll
            for (int t = 0; t < 2; ++t) *(uint4*)&Bs[srowW + t * 8][sslot * 8] = rb[t];
        }
    }

    if (!vmode) {
        // Q/K transposed: feature nb..nb+3 consecutive in acc regs
        const float scl = (c == 0) ? QSCL : 1.0f;
        u16* dst = (c == 0) ? Qo : Ko;
#pragma unroll
        for (int j = 0; j < 4; ++j) {
            const int nb = n0 + j * 16 + lh * 4;
            const float4 b4 = *(const float4*)&bias[nb];
            const int h  = (nb >> 6) & 15;
            const int d0 = nb & 63;
#pragma unroll
            for (int i = 0; i < 2; ++i) {
                const int tok = m0 + wv * 32 + i * 16 + ln;
                const int t = tok >> 1, b = tok & 1;
                uint2 pk;
                pk.x = pkrtz((acc[i][j][0] + b4.x) * scl, (acc[i][j][1] + b4.y) * scl);
                pk.y = pkrtz((acc[i][j][2] + b4.z) * scl, (acc[i][j][3] + b4.w) * scl);
                *(uint2*)&dst[(((size_t)b * NHEAD + h) * TSEQ + t) * DHEAD + d0] = pk;
            }
        }
    } else {
        // V normal: rows = token (lh*4+p), cols = feature (ln) -> V^T stores
#pragma unroll
        for (int j = 0; j < 4; ++j) {
            const int col = n0 + j * 16 + ln;
            const float bc = bias[col];
            const int h = (col >> 6) & 15;
            const int d = col & 63;
#pragma unroll
            for (int i = 0; i < 2; ++i) {
                const int mb = m0 + wv * 32 + i * 16 + lh * 4;
                const int t0 = mb >> 1;
                const u32 e0 = pkrtz(acc[i][j][0] + bc, acc[i][j][2] + bc);  // b=0
                const u32 e1 = pkrtz(acc[i][j][1] + bc, acc[i][j][3] + bc);  // b=1
                *(u32*)&Vo[(((size_t)0 * NHEAD + h) * DHEAD + d) * TSEQ + t0] = e0;
                *(u32*)&Vo[(((size_t)1 * NHEAD + h) * DHEAD + d) * TSEQ + t0] = e1;
            }
        }
    }
}

// ---------------------------------------------------------------------------
// out-proj GEMM: 64x64 tile, BK=64, grid 1024 = 4 blocks/CU.
// Same register-prefetch staging as gemm_qkv.
// Transposed orientation -> float4 fp32 stores of C = A*W^T + bias.
// ---------------------------------------------------------------------------
__global__ __launch_bounds__(256)
void gemm_out64(const u16* __restrict__ A, const u16* __restrict__ W,
                const float* __restrict__ bias, float* __restrict__ Cout,
                int M, int N, int K)
{
    __shared__ __align__(16) u16 As[64][64];
    __shared__ __align__(16) u16 Bs[64][64];

    const int tid  = threadIdx.x;
    const int lane = tid & 63;
    const int wv   = tid >> 6;
    const int ln   = lane & 15, lh = lane >> 4;
    const int m0   = blockIdx.y * 64;
    const int n0   = blockIdx.x * 64;

    // staging slots: thread covers rows {tid>>3, 32+(tid>>3)}, slot tid&7
    const int srow  = tid >> 3;                 // 0..31
    const int sslot = tid & 7;
    const int g0 = (sslot ^ (srow & 7)) * 8;
    const int g1 = (sslot ^ ((srow + 32) & 7)) * 8;

    const u16* gA0 = A + (size_t)(m0 + srow) * K + g0;
    const u16* gA1 = A + (size_t)(m0 + srow + 32) * K + g1;
    const u16* gW0 = W + (size_t)(n0 + srow) * K + g0;
    const u16* gW1 = W + (size_t)(n0 + srow + 32) * K + g1;

    const floatx4 zero4 = {0.0f, 0.0f, 0.0f, 0.0f};
    floatx4 acc[4];
#pragma unroll
    for (int j = 0; j < 4; ++j) acc[j] = zero4;

    uint4 ra0, ra1, rb0, rb1;
    ra0 = *(const uint4*)gA0; ra1 = *(const uint4*)gA1;
    rb0 = *(const uint4*)gW0; rb1 = *(const uint4*)gW1;
    *(uint4*)&As[srow][sslot * 8]      = ra0;
    *(uint4*)&As[srow + 32][sslot * 8] = ra1;
    *(uint4*)&Bs[srow][sslot * 8]      = rb0;
    *(uint4*)&Bs[srow + 32][sslot * 8] = rb1;

    const int NIT = K / 64;
    for (int it = 0; it < NIT; ++it) {
        __syncthreads();                       // publish tile it

        if (it + 1 < NIT) {
            const int k0 = (it + 1) * 64;
            ra0 = *(const uint4*)(gA0 + k0); ra1 = *(const uint4*)(gA1 + k0);
            rb0 = *(const uint4*)(gW0 + k0); rb1 = *(const uint4*)(gW1 + k0);
        }

#pragma unroll
        for (int ks = 0; ks < 2; ++ks) {
            const int arow = wv * 16 + ln;
            half8 xf = *(const half8*)&As[arow][(((ks << 2) | lh) ^ (arow & 7)) * 8];
#pragma unroll
            for (int j = 0; j < 4; ++j) {
                const int row = j * 16 + ln;
                half8 wf = *(const half8*)&Bs[row][(((ks << 2) | lh) ^ (row & 7)) * 8];
                acc[j] = __builtin_amdgcn_mfma_f32_16x16x32_f16(wf, xf, acc[j], 0, 0, 0);
            }
        }

        __syncthreads();                       // reads done
        if (it + 1 < NIT) {
            *(uint4*)&As[srow][sslot * 8]      = ra0;
            *(uint4*)&As[srow + 32][sslot * 8] = ra1;
            *(uint4*)&Bs[srow][sslot * 8]      = rb0;
            *(uint4*)&Bs[srow + 32][sslot * 8] = rb1;
        }
    }

    // transposed: D rows = feature (lh*4+p), cols = token (ln)
#pragma unroll
    for (int j = 0; j < 4; ++j) {
        const int fb = n0 + j * 16 + lh * 4;
        const float4 b4 = *(const float4*)&bias[fb];
        const int tok = m0 + wv * 16 + ln;
        float4 v;
        v.x = acc[j][0] + b4.x;
        v.y = acc[j][1] + b4.y;
        v.z = acc[j][2] + b4.z;
        v.w = acc[j][3] + b4.w;
        *(float4*)&Cout[(size_t)tok * N + fb] = v;
    }
}

// ---------------------------------------------------------------------------
// S^T-formulation MFMA flash attention, 64-q-row tiles, one tile per block.
// (unchanged from R9 — measured LDS-throughput-bound near structural floor)
// ---------------------------------------------------------------------------
__global__ __launch_bounds__(256)
void flash_f16(const u16* __restrict__ Q, const u16* __restrict__ K,
               const u16* __restrict__ Vt, u16* __restrict__ AV,
               const int* __restrict__ causal_p)
{
    // layout: rows 0..63 = Q then P (aliased); 64..127 = K; 128..207 = V^T+ones
    __shared__ __align__(16) u16 smem[(64 + 64 + 80) * 72];
    u16 (* __restrict__ QPs)[72] = (u16(*)[72])smem;
    u16 (* __restrict__ Ks)[72]  = (u16(*)[72])(smem + 64 * 72);
    u16 (* __restrict__ Vs)[72]  = (u16(*)[72])(smem + 128 * 72);

    const int tid  = threadIdx.x;
    const int lane = tid & 63;
    const int wv   = tid >> 6;
    const int ln   = lane & 15, lh = lane >> 4;

    const int phase = blockIdx.x >> 8;          // 0..3
    const int slot  = blockIdx.x & 255;
    const int bh    = slot & 31;                // b*16 + h
    const int jq    = slot >> 5;                // 0..7
    int qb;
    if      (phase == 0) qb = 31 - jq;
    else if (phase == 1) qb = jq;
    else if (phase == 2) qb = 23 - jq;
    else                 qb = 8 + jq;

    const int b = bh >> 4;
    const int h = bh & 15;
    const int causal = causal_p[0];

    const u16* Qg = Q  + (size_t)bh * TSEQ * DHEAD;
    const u16* Kg = K  + (size_t)bh * TSEQ * DHEAD;
    const u16* Vg = Vt + (size_t)bh * DHEAD * TSEQ;

    const int lrow = tid >> 3;                  // 0..31
    const int lc8  = (tid & 7) * 8;

    // Q tile -> LDS (QPs); ones rows 64..79 of Vs; prefetch K/V^T block 0
    *(uint4*)&QPs[lrow][lc8]      = *(const uint4*)(Qg + (size_t)(qb * 64 + lrow) * DHEAD + lc8);
    *(uint4*)&QPs[lrow + 32][lc8] = *(const uint4*)(Qg + (size_t)(qb * 64 + lrow + 32) * DHEAD + lc8);
    for (int idx = tid; idx < 16 * 72; idx += 256) {
        const int rr = idx / 72, cc = idx % 72;
        Vs[64 + rr][cc] = (rr == 0) ? (u16)0x3C00 : (u16)0;   // fp16 1.0 / 0
    }
    uint4 kreg0 = *(const uint4*)(Kg + (size_t)lrow * DHEAD + lc8);
    uint4 kreg1 = *(const uint4*)(Kg + (size_t)(lrow + 32) * DHEAD + lc8);
    uint4 vreg0 = *(const uint4*)(Vg + (size_t)lrow * TSEQ + lc8);
    uint4 vreg1 = *(const uint4*)(Vg + (size_t)(lrow + 32) * TSEQ + lc8);
    __syncthreads();

    const int qr0  = wv * 16;
    const int qloc = qr0 + ln;                  // this lane's q-row (local)
    const half8 bQ0 = *(const half8*)&QPs[qloc][lh * 8];
    const half8 bQ1 = *(const half8*)&QPs[qloc][32 + lh * 8];
    const half8 bO0 = *(const half8*)&Vs[64 + ln][lh * 8];
    const half8 bO1 = *(const half8*)&Vs[64 + ln][32 + lh * 8];

    const floatx4 zero4 = {0.0f, 0.0f, 0.0f, 0.0f};
    floatx4 o[4], o4;
#pragma unroll
    for (int j = 0; j < 4; ++j) o[j] = zero4;
    o4 = zero4;
    float m_i = -3.0e38f;

    const int kb_end = causal ? qb : (TSEQ / 64 - 1);
    for (int kb = 0; kb <= kb_end; ++kb) {
        // stage prefetched regs -> LDS (straight copies)
        *(uint4*)&Ks[lrow][lc8]      = kreg0;
        *(uint4*)&Ks[lrow + 32][lc8] = kreg1;
        *(uint4*)&Vs[lrow][lc8]      = vreg0;
        *(uint4*)&Vs[lrow + 32][lc8] = vreg1;
        __syncthreads();

        // prefetch next K/V^T block (hidden behind compute)
        if (kb < kb_end) {
            const size_t nk = (size_t)(kb + 1) * 64;
            kreg0 = *(const uint4*)(Kg + (nk + lrow) * DHEAD + lc8);
            kreg1 = *(const uint4*)(Kg + (nk + lrow + 32) * DHEAD + lc8);
            vreg0 = *(const uint4*)(Vg + (size_t)lrow * TSEQ + nk + lc8);
            vreg1 = *(const uint4*)(Vg + (size_t)(lrow + 32) * TSEQ + nk + lc8);
        }

        // S^T = K Q^T : s[j][r] = S[key = 16j+4lh+r][q = qloc]
        floatx4 s[4];
#pragma unroll
        for (int j = 0; j < 4; ++j) {
            half8 aK0 = *(const half8*)&Ks[j * 16 + ln][lh * 8];
            half8 aK1 = *(const half8*)&Ks[j * 16 + ln][32 + lh * 8];
            floatx4 z = zero4;
            z = __builtin_amdgcn_mfma_f32_16x16x32_f16(aK0, bQ0, z, 0, 0, 0);
            z = __builtin_amdgcn_mfma_f32_16x16x32_f16(aK1, bQ1, z, 0, 0, 0);
            s[j] = z;
        }
        if ((causal != 0) && (kb == qb)) {
#pragma unroll
            for (int j = 0; j < 4; ++j)
#pragma unroll
                for (int r = 0; r < 4; ++r)
                    if (j * 16 + lh * 4 + r > qloc) s[j][r] -= MSK;
        }

        // per-lane online max (one q-row per lane; reduce across lh groups)
        float mx = m_i;
#pragma unroll
        for (int j = 0; j < 4; ++j)
#pragma unroll
            for (int r = 0; r < 4; ++r) mx = fmaxf(mx, s[j][r]);
        mx = fmaxf(mx, __shfl_xor(mx, 16));
        mx = fmaxf(mx, __shfl_xor(mx, 32));
        const float alpha = exp2f(m_i - mx);
        m_i = mx;

        // P = exp2(s - mx), packed straight to LDS (rows wave-private)
#pragma unroll
        for (int j = 0; j < 4; ++j) {
            uint2 pk;
            pk.x = pkrtz(exp2f(s[j][0] - mx), exp2f(s[j][1] - mx));
            pk.y = pkrtz(exp2f(s[j][2] - mx), exp2f(s[j][3] - mx));
            *(uint2*)&QPs[qloc][j * 16 + lh * 4] = pk;
        }

        // rescale o (and o4): o[j][r] is q-row (lh*4+r); alpha at lane 4lh+r
        float a_r[4];
#pragma unroll
        for (int r = 0; r < 4; ++r) a_r[r] = __shfl(alpha, lh * 4 + r);
#pragma unroll
        for (int j = 0; j < 4; ++j)
#pragma unroll
            for (int r = 0; r < 4; ++r) o[j][r] *= a_r[r];
#pragma unroll
        for (int r = 0; r < 4; ++r) o4[r] *= a_r[r];

        // O += P V ; o4 += P * ones (row-sums -> l_i recurrence for free)
        half8 aP0 = *(const half8*)&QPs[qloc][lh * 8];
        half8 aP1 = *(const half8*)&QPs[qloc][32 + lh * 8];
#pragma unroll
        for (int j = 0; j < 4; ++j) {
            half8 bV0 = *(const half8*)&Vs[j * 16 + ln][lh * 8];
            half8 bV1 = *(const half8*)&Vs[j * 16 + ln][32 + lh * 8];
            o[j] = __builtin_amdgcn_mfma_f32_16x16x32_f16(aP0, bV0, o[j], 0, 0, 0);
            o[j] = __builtin_amdgcn_mfma_f32_16x16x32_f16(aP1, bV1, o[j], 0, 0, 0);
        }
        o4 = __builtin_amdgcn_mfma_f32_16x16x32_f16(aP0, bO0, o4, 0, 0, 0);
        o4 = __builtin_amdgcn_mfma_f32_16x16x32_f16(aP1, bO1, o4, 0, 0, 0);

        __syncthreads();   // all reads of Ks/Vs/QPs done before next staging
    }

    // epilogue: o rows = q-local lh*4+r, cols d = 16j+ln.
#pragma unroll
    for (int r = 0; r < 4; ++r) {
        const float lr = __shfl(o4[r], lane & 48);
        const float il = 1.0f / lr;
        const int qrow = qb * 64 + qr0 + lh * 4 + r;
#pragma unroll
        for (int j = 0; j < 4; ++j) {
            const int d = j * 16 + ln;
            AV[((size_t)qrow * BB + b) * DMODEL + h * 64 + d] = f2h(o[j][r] * il);
        }
    }
}

// ---------------------------------------------------------------------------
extern "C" void kernel_launch(void* const* d_in, const int* in_sizes, int n_in,
                              void* d_out, int out_size, void* d_ws, size_t ws_size,
                              hipStream_t stream)
{
    const float* x      = (const float*)d_in[0];
    const float* qkv_w  = (const float*)d_in[1];
    const float* qkv_b  = (const float*)d_in[2];
    const float* out_w  = (const float*)d_in[3];
    const float* out_b  = (const float*)d_in[4];
    const int*   is_causal = (const int*)d_in[5];
    float* out = (float*)d_out;

    u16* ws   = (u16*)d_ws;
    u16* xb   = ws;                       // 4096*1024
    u16* wqkv = xb   + (size_t)4194304;   // 3072*1024
    u16* wout = wqkv + (size_t)3145728;   // 1024*1024
    u16* Qh   = wout + (size_t)1048576;   // [b][h][t][d]
    u16* Kh   = Qh   + (size_t)4194304;   // [b][h][t][d]
    u16* Vth  = Kh   + (size_t)4194304;   // [b][h][d][t]
    u16* AVh  = Vth  + (size_t)4194304;   // 4096*1024

    cast3_f32_f16<<<8192, 256, 0, stream>>>(x, xb, qkv_w, wqkv, out_w, wout);

    // QKV projection: M=4096, N=3072, K=1024 (Q scaled, V transposed)
    gemm_qkv<<<dim3(3 * DMODEL / 64, MROWS / 128), 256, 0, stream>>>(
        xb, wqkv, qkv_b, Qh, Kh, Vth, MROWS, 3 * DMODEL, DMODEL);

    // flash attention: 1024 blocks, one 64-row q-tile each, 4 resident/CU
    flash_f16<<<1024, 256, 0, stream>>>(Qh, Kh, Vth, AVh, is_causal);

    // output projection: M=4096, N=1024, K=1024, 64x64 tiles -> 4 blocks/CU
    gemm_out64<<<dim3(DMODEL / 64, MROWS / 64), 256, 0, stream>>>(
        AVh, wout, out_b, out, MROWS, DMODEL, DMODEL);
}

// Round 11
// 210.609 us; speedup vs baseline: 1.4673x; 1.4673x over previous
//
#include <hip/hip_runtime.h>
#include <math.h>

#define TSEQ   2048
#define BB     2
#define DMODEL 1024
#define NHEAD  16
#define DHEAD  64
#define MROWS  (TSEQ * BB)   // 4096
#define NQB    (TSEQ / 64)   // 32 query tiles per (b,h)

typedef __attribute__((ext_vector_type(8))) _Float16 half8;
typedef __attribute__((ext_vector_type(4))) float    floatx4;
typedef unsigned short u16;
typedef unsigned int   u32;

#define QSCL 11.5415603f   /* 8 * log2(e): Q pre-scale -> exp2-domain scores */
#define MSK  1442695.0f    /* 1e6 * log2(e) */

__device__ __forceinline__ u16 f2h(float f) {
    union { _Float16 h; u16 u; } cv;
    cv.h = (_Float16)f;
    return cv.u;
}

// packed fp32x2 -> fp16x2 (round-to-zero) as u32
__device__ __forceinline__ u32 pkrtz(float a, float b) {
    typedef __attribute__((ext_vector_type(2))) __fp16 fp16x2;
    union { fp16x2 h; u32 u; } cv;
    cv.h = __builtin_amdgcn_cvt_pkrtz(a, b);
    return cv.u;
}

// ---------------------------------------------------------------------------
// one-launch fp32 -> fp16 cast of x, qkv_w, out_w
// float4 units: x 1048576, qkv_w 786432, out_w 262144 (total 2097152)
// ---------------------------------------------------------------------------
__global__ __launch_bounds__(256)
void cast3_f32_f16(const float* __restrict__ a, u16* __restrict__ oa,
                   const float* __restrict__ b, u16* __restrict__ ob,
                   const float* __restrict__ c, u16* __restrict__ oc)
{
    int i = blockIdx.x * 256 + threadIdx.x;
    const float* src; u16* dst; int off;
    if (i < 1048576)      { src = a; dst = oa; off = 0; }
    else if (i < 1835008) { src = b; dst = ob; off = 1048576; }
    else                  { src = c; dst = oc; off = 1835008; }
    int j = i - off;
    float4 v = ((const float4*)src)[j];
    ushort4 o;
    o.x = f2h(v.x); o.y = f2h(v.y); o.z = f2h(v.z); o.w = f2h(v.w);
    ((ushort4*)dst)[j] = o;
}

// ---------------------------------------------------------------------------
// QKV GEMM: 128(M) x 64(N) tile, BK=64, XOR-swizzled LDS.
// Staging mirrors flash_f16 EXACTLY (that version is spill-free at 60 VGPRs):
//   loop top: ds_write named-scalar regs -> barrier -> conditional prefetch
//   of tile it+1 into the same scalars -> compute -> barrier.
// __launch_bounds__(256,4): cap 128 VGPRs, target 4 waves/SIMD -> the
// allocator cannot repeat R10's spill-for-occupancy choice (304 MB scratch).
// c<2 (Q,K): transposed orientation, packed uint2 fp16 -> [b][h][t][d],
//            Q scaled by QSCL;  c==2 (V): normal -> V^T [b][h][d][t].
// ---------------------------------------------------------------------------
__global__ __launch_bounds__(256, 4)
void gemm_qkv(const u16* __restrict__ A, const u16* __restrict__ W,
              const float* __restrict__ bias,
              u16* __restrict__ Qo, u16* __restrict__ Ko, u16* __restrict__ Vo,
              int M, int N, int K)
{
    __shared__ __align__(16) u16 As[128][64];
    __shared__ __align__(16) u16 Bs[64][64];

    const int tid  = threadIdx.x;
    const int lane = tid & 63;
    const int wv   = tid >> 6;
    const int ln   = lane & 15, lh = lane >> 4;
    const int m0   = blockIdx.y * 128;
    const int n0   = blockIdx.x * 64;

    const int c = n0 >> 10;                  // 0,1,2 = q,k,v (block-uniform)
    const bool vmode = (c == 2);             // normal orientation

    const int srowA = wv * 32 + (lane >> 3);   // + {0,8,16,24}
    const int srowW = wv * 16 + (lane >> 3);   // + {0,8}
    const int sslot = lane & 7;
    const int gcol  = (sslot ^ ((lane >> 3) & 7)) * 8;   // row&7 == (lane>>3)&7

    const u16* gA = A + (size_t)(m0 + srowA) * K + gcol;
    const u16* gW = W + (size_t)(n0 + srowW) * K + gcol;

    const floatx4 zero4 = {0.0f, 0.0f, 0.0f, 0.0f};
    floatx4 acc[2][4];
#pragma unroll
    for (int i = 0; i < 2; ++i)
#pragma unroll
        for (int j = 0; j < 4; ++j) acc[i][j] = zero4;

    // prologue: tile 0 -> named scalar regs
    uint4 ra0 = *(const uint4*)(gA);
    uint4 ra1 = *(const uint4*)(gA + 8 * (size_t)K);
    uint4 ra2 = *(const uint4*)(gA + 16 * (size_t)K);
    uint4 ra3 = *(const uint4*)(gA + 24 * (size_t)K);
    uint4 rb0 = *(const uint4*)(gW);
    uint4 rb1 = *(const uint4*)(gW + 8 * (size_t)K);

    const int NIT = K / 64;
    for (int it = 0; it < NIT; ++it) {
        // stage regs -> LDS (flash-style loop top)
        *(uint4*)&As[srowA][sslot * 8]      = ra0;
        *(uint4*)&As[srowA + 8][sslot * 8]  = ra1;
        *(uint4*)&As[srowA + 16][sslot * 8] = ra2;
        *(uint4*)&As[srowA + 24][sslot * 8] = ra3;
        *(uint4*)&Bs[srowW][sslot * 8]      = rb0;
        *(uint4*)&Bs[srowW + 8][sslot * 8]  = rb1;
        __syncthreads();

        // prefetch tile it+1 (latency hidden behind compute below)
        if (it + 1 < NIT) {
            const int k0 = (it + 1) * 64;
            ra0 = *(const uint4*)(gA + k0);
            ra1 = *(const uint4*)(gA + 8 * (size_t)K + k0);
            ra2 = *(const uint4*)(gA + 16 * (size_t)K + k0);
            ra3 = *(const uint4*)(gA + 24 * (size_t)K + k0);
            rb0 = *(const uint4*)(gW + k0);
            rb1 = *(const uint4*)(gW + 8 * (size_t)K + k0);
        }

#pragma unroll
        for (int ks = 0; ks < 2; ++ks) {
            half8 xf[2], wf[4];
#pragma unroll
            for (int i = 0; i < 2; ++i) {
                const int row = wv * 32 + i * 16 + ln;
                xf[i] = *(const half8*)&As[row][(((ks << 2) | lh) ^ (row & 7)) * 8];
            }
#pragma unroll
            for (int j = 0; j < 4; ++j) {
                const int row = j * 16 + ln;
                wf[j] = *(const half8*)&Bs[row][(((ks << 2) | lh) ^ (row & 7)) * 8];
            }
            if (vmode) {
#pragma unroll
                for (int i = 0; i < 2; ++i)
#pragma unroll
                    for (int j = 0; j < 4; ++j)
                        acc[i][j] = __builtin_amdgcn_mfma_f32_16x16x32_f16(xf[i], wf[j], acc[i][j], 0, 0, 0);
            } else {
#pragma unroll
                for (int i = 0; i < 2; ++i)
#pragma unroll
                    for (int j = 0; j < 4; ++j)
                        acc[i][j] = __builtin_amdgcn_mfma_f32_16x16x32_f16(wf[j], xf[i], acc[i][j], 0, 0, 0);
            }
        }
        __syncthreads();                       // all reads of tile it done
    }

    if (!vmode) {
        // Q/K transposed: feature nb..nb+3 consecutive in acc regs
        const float scl = (c == 0) ? QSCL : 1.0f;
        u16* dst = (c == 0) ? Qo : Ko;
#pragma unroll
        for (int j = 0; j < 4; ++j) {
            const int nb = n0 + j * 16 + lh * 4;
            const float4 b4 = *(const float4*)&bias[nb];
            const int h  = (nb >> 6) & 15;
            const int d0 = nb & 63;
#pragma unroll
            for (int i = 0; i < 2; ++i) {
                const int tok = m0 + wv * 32 + i * 16 + ln;
                const int t = tok >> 1, b = tok & 1;
                uint2 pk;
                pk.x = pkrtz((acc[i][j][0] + b4.x) * scl, (acc[i][j][1] + b4.y) * scl);
                pk.y = pkrtz((acc[i][j][2] + b4.z) * scl, (acc[i][j][3] + b4.w) * scl);
                *(uint2*)&dst[(((size_t)b * NHEAD + h) * TSEQ + t) * DHEAD + d0] = pk;
            }
        }
    } else {
        // V normal: rows = token (lh*4+p), cols = feature (ln) -> V^T stores
#pragma unroll
        for (int j = 0; j < 4; ++j) {
            const int col = n0 + j * 16 + ln;
            const float bc = bias[col];
            const int h = (col >> 6) & 15;
            const int d = col & 63;
#pragma unroll
            for (int i = 0; i < 2; ++i) {
                const int mb = m0 + wv * 32 + i * 16 + lh * 4;
                const int t0 = mb >> 1;
                const u32 e0 = pkrtz(acc[i][j][0] + bc, acc[i][j][2] + bc);  // b=0
                const u32 e1 = pkrtz(acc[i][j][1] + bc, acc[i][j][3] + bc);  // b=1
                *(u32*)&Vo[(((size_t)0 * NHEAD + h) * DHEAD + d) * TSEQ + t0] = e0;
                *(u32*)&Vo[(((size_t)1 * NHEAD + h) * DHEAD + d) * TSEQ + t0] = e1;
            }
        }
    }
}

// ---------------------------------------------------------------------------
// out-proj GEMM: 64x64 tile, BK=64, grid 1024 = 4 blocks/CU.
// Same flash-style staging rotation, named scalars, launch_bounds(256,4).
// Transposed orientation -> float4 fp32 stores of C = A*W^T + bias.
// ---------------------------------------------------------------------------
__global__ __launch_bounds__(256, 4)
void gemm_out64(const u16* __restrict__ A, const u16* __restrict__ W,
                const float* __restrict__ bias, float* __restrict__ Cout,
                int M, int N, int K)
{
    __shared__ __align__(16) u16 As[64][64];
    __shared__ __align__(16) u16 Bs[64][64];

    const int tid  = threadIdx.x;
    const int lane = tid & 63;
    const int wv   = tid >> 6;
    const int ln   = lane & 15, lh = lane >> 4;
    const int m0   = blockIdx.y * 64;
    const int n0   = blockIdx.x * 64;

    const int srow  = tid >> 3;                 // 0..31
    const int sslot = tid & 7;
    const int g0 = (sslot ^ (srow & 7)) * 8;    // (srow+32)&7 == srow&7

    const u16* gA0 = A + (size_t)(m0 + srow) * K + g0;
    const u16* gA1 = A + (size_t)(m0 + srow + 32) * K + g0;
    const u16* gW0 = W + (size_t)(n0 + srow) * K + g0;
    const u16* gW1 = W + (size_t)(n0 + srow + 32) * K + g0;

    const floatx4 zero4 = {0.0f, 0.0f, 0.0f, 0.0f};
    floatx4 acc[4];
#pragma unroll
    for (int j = 0; j < 4; ++j) acc[j] = zero4;

    uint4 ra0 = *(const uint4*)gA0;
    uint4 ra1 = *(const uint4*)gA1;
    uint4 rb0 = *(const uint4*)gW0;
    uint4 rb1 = *(const uint4*)gW1;

    const int NIT = K / 64;
    for (int it = 0; it < NIT; ++it) {
        *(uint4*)&As[srow][sslot * 8]      = ra0;
        *(uint4*)&As[srow + 32][sslot * 8] = ra1;
        *(uint4*)&Bs[srow][sslot * 8]      = rb0;
        *(uint4*)&Bs[srow + 32][sslot * 8] = rb1;
        __syncthreads();

        if (it + 1 < NIT) {
            const int k0 = (it + 1) * 64;
            ra0 = *(const uint4*)(gA0 + k0); ra1 = *(const uint4*)(gA1 + k0);
            rb0 = *(const uint4*)(gW0 + k0); rb1 = *(const uint4*)(gW1 + k0);
        }

#pragma unroll
        for (int ks = 0; ks < 2; ++ks) {
            const int arow = wv * 16 + ln;
            half8 xf = *(const half8*)&As[arow][(((ks << 2) | lh) ^ (arow & 7)) * 8];
#pragma unroll
            for (int j = 0; j < 4; ++j) {
                const int row = j * 16 + ln;
                half8 wf = *(const half8*)&Bs[row][(((ks << 2) | lh) ^ (row & 7)) * 8];
                acc[j] = __builtin_amdgcn_mfma_f32_16x16x32_f16(wf, xf, acc[j], 0, 0, 0);
            }
        }
        __syncthreads();
    }

    // transposed: D rows = feature (lh*4+p), cols = token (ln)
#pragma unroll
    for (int j = 0; j < 4; ++j) {
        const int fb = n0 + j * 16 + lh * 4;
        const float4 b4 = *(const float4*)&bias[fb];
        const int tok = m0 + wv * 16 + ln;
        float4 v;
        v.x = acc[j][0] + b4.x;
        v.y = acc[j][1] + b4.y;
        v.z = acc[j][2] + b4.z;
        v.w = acc[j][3] + b4.w;
        *(float4*)&Cout[(size_t)tok * N + fb] = v;
    }
}

// ---------------------------------------------------------------------------
// S^T-formulation MFMA flash attention, 64-q-row tiles, one tile per block.
// (unchanged from R9 — measured LDS-throughput-bound near structural floor)
// ---------------------------------------------------------------------------
__global__ __launch_bounds__(256)
void flash_f16(const u16* __restrict__ Q, const u16* __restrict__ K,
               const u16* __restrict__ Vt, u16* __restrict__ AV,
               const int* __restrict__ causal_p)
{
    // layout: rows 0..63 = Q then P (aliased); 64..127 = K; 128..207 = V^T+ones
    __shared__ __align__(16) u16 smem[(64 + 64 + 80) * 72];
    u16 (* __restrict__ QPs)[72] = (u16(*)[72])smem;
    u16 (* __restrict__ Ks)[72]  = (u16(*)[72])(smem + 64 * 72);
    u16 (* __restrict__ Vs)[72]  = (u16(*)[72])(smem + 128 * 72);

    const int tid  = threadIdx.x;
    const int lane = tid & 63;
    const int wv   = tid >> 6;
    const int ln   = lane & 15, lh = lane >> 4;

    const int phase = blockIdx.x >> 8;          // 0..3
    const int slot  = blockIdx.x & 255;
    const int bh    = slot & 31;                // b*16 + h
    const int jq    = slot >> 5;                // 0..7
    int qb;
    if      (phase == 0) qb = 31 - jq;
    else if (phase == 1) qb = jq;
    else if (phase == 2) qb = 23 - jq;
    else                 qb = 8 + jq;

    const int b = bh >> 4;
    const int h = bh & 15;
    const int causal = causal_p[0];

    const u16* Qg = Q  + (size_t)bh * TSEQ * DHEAD;
    const u16* Kg = K  + (size_t)bh * TSEQ * DHEAD;
    const u16* Vg = Vt + (size_t)bh * DHEAD * TSEQ;

    const int lrow = tid >> 3;                  // 0..31
    const int lc8  = (tid & 7) * 8;

    // Q tile -> LDS (QPs); ones rows 64..79 of Vs; prefetch K/V^T block 0
    *(uint4*)&QPs[lrow][lc8]      = *(const uint4*)(Qg + (size_t)(qb * 64 + lrow) * DHEAD + lc8);
    *(uint4*)&QPs[lrow + 32][lc8] = *(const uint4*)(Qg + (size_t)(qb * 64 + lrow + 32) * DHEAD + lc8);
    for (int idx = tid; idx < 16 * 72; idx += 256) {
        const int rr = idx / 72, cc = idx % 72;
        Vs[64 + rr][cc] = (rr == 0) ? (u16)0x3C00 : (u16)0;   // fp16 1.0 / 0
    }
    uint4 kreg0 = *(const uint4*)(Kg + (size_t)lrow * DHEAD + lc8);
    uint4 kreg1 = *(const uint4*)(Kg + (size_t)(lrow + 32) * DHEAD + lc8);
    uint4 vreg0 = *(const uint4*)(Vg + (size_t)lrow * TSEQ + lc8);
    uint4 vreg1 = *(const uint4*)(Vg + (size_t)(lrow + 32) * TSEQ + lc8);
    __syncthreads();

    const int qr0  = wv * 16;
    const int qloc = qr0 + ln;                  // this lane's q-row (local)
    const half8 bQ0 = *(const half8*)&QPs[qloc][lh * 8];
    const half8 bQ1 = *(const half8*)&QPs[qloc][32 + lh * 8];
    const half8 bO0 = *(const half8*)&Vs[64 + ln][lh * 8];
    const half8 bO1 = *(const half8*)&Vs[64 + ln][32 + lh * 8];

    const floatx4 zero4 = {0.0f, 0.0f, 0.0f, 0.0f};
    floatx4 o[4], o4;
#pragma unroll
    for (int j = 0; j < 4; ++j) o[j] = zero4;
    o4 = zero4;
    float m_i = -3.0e38f;

    const int kb_end = causal ? qb : (TSEQ / 64 - 1);
    for (int kb = 0; kb <= kb_end; ++kb) {
        // stage prefetched regs -> LDS (straight copies)
        *(uint4*)&Ks[lrow][lc8]      = kreg0;
        *(uint4*)&Ks[lrow + 32][lc8] = kreg1;
        *(uint4*)&Vs[lrow][lc8]      = vreg0;
        *(uint4*)&Vs[lrow + 32][lc8] = vreg1;
        __syncthreads();

        // prefetch next K/V^T block (hidden behind compute)
        if (kb < kb_end) {
            const size_t nk = (size_t)(kb + 1) * 64;
            kreg0 = *(const uint4*)(Kg + (nk + lrow) * DHEAD + lc8);
            kreg1 = *(const uint4*)(Kg + (nk + lrow + 32) * DHEAD + lc8);
            vreg0 = *(const uint4*)(Vg + (size_t)lrow * TSEQ + nk + lc8);
            vreg1 = *(const uint4*)(Vg + (size_t)(lrow + 32) * TSEQ + nk + lc8);
        }

        // S^T = K Q^T : s[j][r] = S[key = 16j+4lh+r][q = qloc]
        floatx4 s[4];
#pragma unroll
        for (int j = 0; j < 4; ++j) {
            half8 aK0 = *(const half8*)&Ks[j * 16 + ln][lh * 8];
            half8 aK1 = *(const half8*)&Ks[j * 16 + ln][32 + lh * 8];
            floatx4 z = zero4;
            z = __builtin_amdgcn_mfma_f32_16x16x32_f16(aK0, bQ0, z, 0, 0, 0);
            z = __builtin_amdgcn_mfma_f32_16x16x32_f16(aK1, bQ1, z, 0, 0, 0);
            s[j] = z;
        }
        if ((causal != 0) && (kb == qb)) {
#pragma unroll
            for (int j = 0; j < 4; ++j)
#pragma unroll
                for (int r = 0; r < 4; ++r)
                    if (j * 16 + lh * 4 + r > qloc) s[j][r] -= MSK;
        }

        // per-lane online max (one q-row per lane; reduce across lh groups)
        float mx = m_i;
#pragma unroll
        for (int j = 0; j < 4; ++j)
#pragma unroll
            for (int r = 0; r < 4; ++r) mx = fmaxf(mx, s[j][r]);
        mx = fmaxf(mx, __shfl_xor(mx, 16));
        mx = fmaxf(mx, __shfl_xor(mx, 32));
        const float alpha = exp2f(m_i - mx);
        m_i = mx;

        // P = exp2(s - mx), packed straight to LDS (rows wave-private)
#pragma unroll
        for (int j = 0; j < 4; ++j) {
            uint2 pk;
            pk.x = pkrtz(exp2f(s[j][0] - mx), exp2f(s[j][1] - mx));
            pk.y = pkrtz(exp2f(s[j][2] - mx), exp2f(s[j][3] - mx));
            *(uint2*)&QPs[qloc][j * 16 + lh * 4] = pk;
        }

        // rescale o (and o4): o[j][r] is q-row (lh*4+r); alpha at lane 4lh+r
        float a_r[4];
#pragma unroll
        for (int r = 0; r < 4; ++r) a_r[r] = __shfl(alpha, lh * 4 + r);
#pragma unroll
        for (int j = 0; j < 4; ++j)
#pragma unroll
            for (int r = 0; r < 4; ++r) o[j][r] *= a_r[r];
#pragma unroll
        for (int r = 0; r < 4; ++r) o4[r] *= a_r[r];

        // O += P V ; o4 += P * ones (row-sums -> l_i recurrence for free)
        half8 aP0 = *(const half8*)&QPs[qloc][lh * 8];
        half8 aP1 = *(const half8*)&QPs[qloc][32 + lh * 8];
#pragma unroll
        for (int j = 0; j < 4; ++j) {
            half8 bV0 = *(const half8*)&Vs[j * 16 + ln][lh * 8];
            half8 bV1 = *(const half8*)&Vs[j * 16 + ln][32 + lh * 8];
            o[j] = __builtin_amdgcn_mfma_f32_16x16x32_f16(aP0, bV0, o[j], 0, 0, 0);
            o[j] = __builtin_amdgcn_mfma_f32_16x16x32_f16(aP1, bV1, o[j], 0, 0, 0);
        }
        o4 = __builtin_amdgcn_mfma_f32_16x16x32_f16(aP0, bO0, o4, 0, 0, 0);
        o4 = __builtin_amdgcn_mfma_f32_16x16x32_f16(aP1, bO1, o4, 0, 0, 0);

        __syncthreads();   // all reads of Ks/Vs/QPs done before next staging
    }

    // epilogue: o rows = q-local lh*4+r, cols d = 16j+ln.
#pragma unroll
    for (int r = 0; r < 4; ++r) {
        const float lr = __shfl(o4[r], lane & 48);
        const float il = 1.0f / lr;
        const int qrow = qb * 64 + qr0 + lh * 4 + r;
#pragma unroll
        for (int j = 0; j < 4; ++j) {
            const int d = j * 16 + ln;
            AV[((size_t)qrow * BB + b) * DMODEL + h * 64 + d] = f2h(o[j][r] * il);
        }
    }
}

// ---------------------------------------------------------------------------
extern "C" void kernel_launch(void* const* d_in, const int* in_sizes, int n_in,
                              void* d_out, int out_size, void* d_ws, size_t ws_size,
                              hipStream_t stream)
{
    const float* x      = (const float*)d_in[0];
    const float* qkv_w  = (const float*)d_in[1];
    const float* qkv_b  = (const float*)d_in[2];
    const float* out_w  = (const float*)d_in[3];
    const float* out_b  = (const float*)d_in[4];
    const int*   is_causal = (const int*)d_in[5];
    float* out = (float*)d_out;

    u16* ws   = (u16*)d_ws;
    u16* xb   = ws;                       // 4096*1024
    u16* wqkv = xb   + (size_t)4194304;   // 3072*1024
    u16* wout = wqkv + (size_t)3145728;   // 1024*1024
    u16* Qh   = wout + (size_t)1048576;   // [b][h][t][d]
    u16* Kh   = Qh   + (size_t)4194304;   // [b][h][t][d]
    u16* Vth  = Kh   + (size_t)4194304;   // [b][h][d][t]
    u16* AVh  = Vth  + (size_t)4194304;   // 4096*1024

    cast3_f32_f16<<<8192, 256, 0, stream>>>(x, xb, qkv_w, wqkv, out_w, wout);

    // QKV projection: M=4096, N=3072, K=1024 (Q scaled, V transposed)
    gemm_qkv<<<dim3(3 * DMODEL / 64, MROWS / 128), 256, 0, stream>>>(
        xb, wqkv, qkv_b, Qh, Kh, Vth, MROWS, 3 * DMODEL, DMODEL);

    // flash attention: 1024 blocks, one 64-row q-tile each, 4 resident/CU
    flash_f16<<<1024, 256, 0, stream>>>(Qh, Kh, Vth, AVh, is_causal);

    // output projection: M=4096, N=1024, K=1024, 64x64 tiles -> 4 blocks/CU
    gemm_out64<<<dim3(DMODEL / 64, MROWS / 64), 256, 0, stream>>>(
        AVh, wout, out_b, out, MROWS, DMODEL, DMODEL);
}